// Round 9
// baseline (17.252 us; speedup 1.0000x reference)
//
#include <hip/hip_runtime.h>

typedef float v2f __attribute__((ext_vector_type(2)));

// Block = 64 n (lanes) x 4 b-waves, 8 b-iterations/thread. grid=(N/64,B/32)
// = 1024 blocks = 4/CU (16 waves/CU). Per R5 counters: every timed replay
// cold-streams ~63 MB from HBM (L3 flushed between replays) -> the loop is
// memory-bound at ~9.7 us. This round: saturate the HBM pipe from cycle 0
// (3-deep prefetch issued BEFORE the sigmoid setup), and cut wasted traffic
// (nontemporal loads/stores: no reuse per replay, no output RFO).
// Inner math: R6's packed v_pk_fma_f32 path (proven, absmax 3.9e-3).
__global__ __launch_bounds__(256, 4) void lut_kernel(const float* __restrict__ in,
                                                     const float* __restrict__ lut,
                                                     float* __restrict__ out,
                                                     int N) {
    __shared__ __align__(16) float wsm[64][68];   // 16B-aligned rows, conflict-free

    const int t  = threadIdx.x;
    const int nl = t & 63;            // lane = local n
    const int wv = t >> 6;            // wave id 0..3 (parallel b)
    const int n0 = blockIdx.x * 64;
    const int n  = n0 + nl;
    const int b0 = blockIdx.y * 32 + wv;

    // ---- issue 3 iterations of input loads FIRST (saturate HBM from t=0) ----
    const v2f* ip = reinterpret_cast<const v2f*>(in) + ((size_t)b0 * N + n) * 3;
    const size_t st = (size_t)N * 12;             // 4 b-rows in v2f units
    v2f pf[3][3];
    #pragma unroll
    for (int p = 0; p < 3; ++p) {
        const v2f* q = ip + (size_t)p * st;
        pf[p][0] = __builtin_nontemporal_load(q + 0);
        pf[p][1] = __builtin_nontemporal_load(q + 1);
        pf[p][2] = __builtin_nontemporal_load(q + 2);
    }

    // ---- sigmoid(lut) tile -> LDS (coalesced; overlaps in-flight loads) ----
    {
        const float4* lp = reinterpret_cast<const float4*>(lut + (size_t)n0 * 64);
        const int rr = t >> 2, c4 = t & 3;
        #pragma unroll
        for (int p = 0; p < 4; ++p) {
            const int s = c4 + p * 4;             // float4 slot 0..15
            float4 v = lp[rr * 16 + s];           // wave: 4 KB contiguous
            wsm[rr][s * 4 + 0] = 1.0f / (1.0f + __expf(-v.x));
            wsm[rr][s * 4 + 1] = 1.0f / (1.0f + __expf(-v.y));
            wsm[rr][s * 4 + 2] = 1.0f / (1.0f + __expf(-v.z));
            wsm[rr][s * 4 + 3] = 1.0f / (1.0f + __expf(-v.w));
        }
    }
    __syncthreads();

    // ---- this thread's w row -> 32 packed pairs (16 x ds_read_b128) ----
    v2f w2[32];
    #pragma unroll
    for (int k = 0; k < 16; ++k) {
        float4 v = *reinterpret_cast<const float4*>(&wsm[nl][k * 4]);
        w2[2 * k]     = (v2f){v.x, v.y};
        w2[2 * k + 1] = (v2f){v.z, v.w};
    }

    float* op = out + (size_t)b0 * N + n;

    #pragma unroll
    for (int it = 0; it < 8; ++it) {
        const v2f va = pf[it % 3][0], vb = pf[it % 3][1], vc = pf[it % 3][2];
        if (it < 5) {                              // refill slot -> 3-deep steady state
            const v2f* q = ip + (size_t)(it + 3) * st;
            pf[it % 3][0] = __builtin_nontemporal_load(q + 0);
            pf[it % 3][1] = __builtin_nontemporal_load(q + 1);
            pf[it % 3][2] = __builtin_nontemporal_load(q + 2);
        }
        const float x0 = va.x, x1 = va.y, x2 = vb.x,
                    x3 = vb.y, x4 = vc.x, x5 = vc.y;
        const float B0 = 1.0f - x0, B1 = 1.0f - x1, B2 = 1.0f - x2,
                    B3 = 1.0f - x3, B4 = 1.0f - x4, B5 = 1.0f - x5;

        // table idx i = (h<<3)|l; bit==0 -> x, bit==1 -> (1-x)
        const float t01[4] = {x0 * x1, x0 * B1, B0 * x1, B0 * B1};
        const float t34[4] = {x3 * x4, x3 * B4, B3 * x4, B3 * B4};

        v2f tlo2[4];                               // {tlo[2m], tlo[2m+1]}
        #pragma unroll
        for (int m = 0; m < 4; ++m)
            tlo2[m] = (v2f){t34[m] * x5, t34[m] * B5};

        v2f acc2 = (v2f){0.0f, 0.0f};
        #pragma unroll
        for (int h = 0; h < 8; ++h) {
            v2f s2 = tlo2[0] * w2[h * 4 + 0];      // v_pk_fma chains
            s2 += tlo2[1] * w2[h * 4 + 1];
            s2 += tlo2[2] * w2[h * 4 + 2];
            s2 += tlo2[3] * w2[h * 4 + 3];
            const float th = t01[h >> 1] * ((h & 1) ? B2 : x2);
            acc2 += (v2f){th, th} * s2;
        }
        __builtin_nontemporal_store(acc2.x + acc2.y, op + (size_t)it * 4 * N);
    }
}

extern "C" void kernel_launch(void* const* d_in, const int* in_sizes, int n_in,
                              void* d_out, int out_size, void* d_ws, size_t ws_size,
                              hipStream_t stream) {
    const float* inputs = (const float*)d_in[0];   // [B, N, 6] f32
    const float* lut    = (const float*)d_in[1];   // [N, 64]  f32
    float* out = (float*)d_out;                    // [B, N]   f32

    const int lut_sz = in_sizes[1];                // N*64
    const int N = lut_sz / 64;
    const int B = in_sizes[0] / (6 * N);

    dim3 grid(N / 64, B / 32);
    lut_kernel<<<grid, 256, 0, stream>>>(inputs, lut, out, N);
}

// Round 10
// 16.819 us; speedup vs baseline: 1.0257x; 1.0257x over previous
//
#include <hip/hip_runtime.h>

typedef float v2f __attribute__((ext_vector_type(2)));

// DIAGNOSTIC on the best structure (R6, 15.78us) — REP=6 wrap, nothing else
// changed. Purpose: (a) crack rocprof's top-5 (cutoff ~39us) to get THIS
// kernel's FETCH/WRITE/VALUBusy/Occupancy; (b) warm-pass split via
// (dur-15.8)/5; (c) decide whether the WRITE~50MB-for-8MB-output anomaly
// seen in R5 is intrinsic (traffic wall -> we're at roofline) or was spill/
// staging artifact of that kernel.
#define REP 6

__global__ __launch_bounds__(256, 4) void lut_kernel(const float* __restrict__ in,
                                                     const float* __restrict__ lut,
                                                     float* __restrict__ out,
                                                     int N) {
    __shared__ __align__(16) float wsm[64][68];   // 68: 16B-aligned rows, no conflicts

    const int t  = threadIdx.x;
    const int nl = t & 63;            // lane = local n
    const int wv = t >> 6;            // wave id 0..3 (parallel b)
    const int n0 = blockIdx.x * 64;
    const int n  = n0 + nl;
    const int b0 = blockIdx.y * 32 + wv;

    // --- sigmoid(lut[n0+0..63][0..63]) -> LDS, coalesced float4 loads ---
    {
        const float4* lp = reinterpret_cast<const float4*>(lut + (size_t)n0 * 64);
        const int rr = t >> 2, c4 = t & 3;
        #pragma unroll
        for (int p = 0; p < 4; ++p) {
            const int sidx = c4 + p * 4;          // float4 slot 0..15
            float4 v = lp[rr * 16 + sidx];        // wave: 4 KB contiguous
            wsm[rr][sidx * 4 + 0] = 1.0f / (1.0f + __expf(-v.x));
            wsm[rr][sidx * 4 + 1] = 1.0f / (1.0f + __expf(-v.y));
            wsm[rr][sidx * 4 + 2] = 1.0f / (1.0f + __expf(-v.z));
            wsm[rr][sidx * 4 + 3] = 1.0f / (1.0f + __expf(-v.w));
        }
    }
    __syncthreads();

    // --- this thread's w row -> 32 packed pairs (16 x ds_read_b128) ---
    v2f w2[32];
    #pragma unroll
    for (int k = 0; k < 16; ++k) {
        float4 v = *reinterpret_cast<const float4*>(&wsm[nl][k * 4]);
        w2[2 * k]     = (v2f){v.x, v.y};
        w2[2 * k + 1] = (v2f){v.z, v.w};
    }

    const float2* ip = reinterpret_cast<const float2*>(in) + ((size_t)b0 * N + n) * 3;
    const size_t st  = (size_t)N * 12;            // 4 b-rows in float2 units
    float* op = out + (size_t)b0 * N + n;

    #pragma unroll 1
    for (int rep = 0; rep < REP; ++rep) {
        // 2-deep software pipeline of the 24 B/iter input reads
        float2 pf[2][3];
        pf[0][0] = ip[0];      pf[0][1] = ip[1];      pf[0][2] = ip[2];
        pf[1][0] = ip[st + 0]; pf[1][1] = ip[st + 1]; pf[1][2] = ip[st + 2];

        #pragma unroll
        for (int it = 0; it < 8; ++it) {
            const float2 va = pf[it & 1][0], vb = pf[it & 1][1], vc = pf[it & 1][2];
            if (it < 6) {
                const float2* np = ip + (size_t)(it + 2) * st;
                pf[it & 1][0] = np[0]; pf[it & 1][1] = np[1]; pf[it & 1][2] = np[2];
            }
            const float x0 = va.x, x1 = va.y, x2 = vb.x,
                        x3 = vb.y, x4 = vc.x, x5 = vc.y;
            const float B0 = 1.0f - x0, B1 = 1.0f - x1, B2 = 1.0f - x2,
                        B3 = 1.0f - x3, B4 = 1.0f - x4, B5 = 1.0f - x5;

            // table idx i = (h<<3)|l, h=b0b1b2, l=b3b4b5; bit0->x, bit1->1-x
            const float t01[4] = {x0 * x1, x0 * B1, B0 * x1, B0 * B1};
            const float t34[4] = {x3 * x4, x3 * B4, B3 * x4, B3 * B4};

            v2f tlo2[4];                           // {tlo[2m], tlo[2m+1]}
            #pragma unroll
            for (int m = 0; m < 4; ++m)
                tlo2[m] = (v2f){t34[m] * x5, t34[m] * B5};

            v2f acc2 = (v2f){0.0f, 0.0f};
            #pragma unroll
            for (int h = 0; h < 8; ++h) {
                v2f s2 = tlo2[0] * w2[h * 4 + 0];  // v_pk_fma chains
                s2 += tlo2[1] * w2[h * 4 + 1];
                s2 += tlo2[2] * w2[h * 4 + 2];
                s2 += tlo2[3] * w2[h * 4 + 3];
                const float th = t01[h >> 1] * ((h & 1) ? B2 : x2);
                acc2 += (v2f){th, th} * s2;
            }
            op[(size_t)it * 4 * N] = acc2.x + acc2.y;
        }
    }
}

extern "C" void kernel_launch(void* const* d_in, const int* in_sizes, int n_in,
                              void* d_out, int out_size, void* d_ws, size_t ws_size,
                              hipStream_t stream) {
    const float* inputs = (const float*)d_in[0];   // [B, N, 6] f32
    const float* lut    = (const float*)d_in[1];   // [N, 64]  f32
    float* out = (float*)d_out;                    // [B, N]   f32

    const int lut_sz = in_sizes[1];                // N*64
    const int N = lut_sz / 64;
    const int B = in_sizes[0] / (6 * N);

    dim3 grid(N / 64, B / 32);
    lut_kernel<<<grid, 256, 0, stream>>>(inputs, lut, out, N);
}

// Round 11
// 15.505 us; speedup vs baseline: 1.1126x; 1.0847x over previous
//
#include <hip/hip_runtime.h>

typedef __fp16 h2 __attribute__((ext_vector_type(2)));   // matches cvt_pkrtz return

// Block = 64 n (lanes) x 4 b-waves, 8 b-iterations/thread.
// grid = (N/64, B/32) = 1024 blocks = 4/CU (16 waves/CU), launch_bounds(256,4).
// Levers this round (each individually motivated, see journal):
//  - w row as 32 packed f16 pairs (32 VGPR) consumed by v_dot2_f32_f16;
//    tested un-confounded at the proven 8-iter/thread grid (R8 accidentally
//    halved b-amortization).
//  - 4-deep input pipeline (96 B/thread in flight) funded by the freed regs.
//  - issue order lut-loads -> input prefetch -> exp: vmcnt retires FIFO, so
//    the sigma phase doesn't wait behind input loads (R9 had it inverted).
__global__ __launch_bounds__(256, 4) void lut_kernel(const float* __restrict__ in,
                                                     const float* __restrict__ lut,
                                                     float* __restrict__ out,
                                                     int N) {
    __shared__ __align__(16) __fp16 wsm[64][72];  // 144 B rows, b128-friendly pad

    const int t  = threadIdx.x;
    const int nl = t & 63;            // lane = local n
    const int wv = t >> 6;            // wave id 0..3 (parallel b)
    const int n0 = blockIdx.x * 64;
    const int n  = n0 + nl;
    const int b0 = blockIdx.y * 32 + wv;

    // ---- 1) issue lut tile loads FIRST (consumed first; FIFO vmcnt) ----
    const float4* lp = reinterpret_cast<const float4*>(lut + (size_t)n0 * 64);
    const int rr = t >> 2, c4 = t & 3;
    float4 lv[4];
    #pragma unroll
    for (int p = 0; p < 4; ++p)
        lv[p] = lp[rr * 16 + (c4 + p * 4)];       // wave: 4 KB contiguous each

    // ---- 2) issue 4 iterations of input prefetch (behind lut in FIFO) ----
    const float2* ip = reinterpret_cast<const float2*>(in) + ((size_t)b0 * N + n) * 3;
    const size_t st  = (size_t)N * 12;            // 4 b-rows in float2 units
    float2 pf[4][3];
    #pragma unroll
    for (int p = 0; p < 4; ++p) {
        const float2* q = ip + (size_t)p * st;
        pf[p][0] = q[0]; pf[p][1] = q[1]; pf[p][2] = q[2];
    }

    // ---- 3) sigma(lut) -> f16 LDS (only waits on the 4 lut loads) ----
    #pragma unroll
    for (int p = 0; p < 4; ++p) {
        const int s = c4 + p * 4;                 // float4 slot 0..15
        h2 a = __builtin_amdgcn_cvt_pkrtz(1.0f / (1.0f + __expf(-lv[p].x)),
                                          1.0f / (1.0f + __expf(-lv[p].y)));
        h2 b = __builtin_amdgcn_cvt_pkrtz(1.0f / (1.0f + __expf(-lv[p].z)),
                                          1.0f / (1.0f + __expf(-lv[p].w)));
        *reinterpret_cast<h2*>(&wsm[rr][s * 4 + 0]) = a;
        *reinterpret_cast<h2*>(&wsm[rr][s * 4 + 2]) = b;
    }
    __syncthreads();

    // ---- this thread's w row: 32 half2 = 32 VGPR (8 x ds_read_b128) ----
    h2 w2[32];
    #pragma unroll
    for (int k = 0; k < 8; ++k) {
        h2 r0 = *reinterpret_cast<const h2*>(&wsm[nl][k * 8 + 0]);
        h2 r1 = *reinterpret_cast<const h2*>(&wsm[nl][k * 8 + 2]);
        h2 r2 = *reinterpret_cast<const h2*>(&wsm[nl][k * 8 + 4]);
        h2 r3 = *reinterpret_cast<const h2*>(&wsm[nl][k * 8 + 6]);
        w2[k * 4 + 0] = r0; w2[k * 4 + 1] = r1;
        w2[k * 4 + 2] = r2; w2[k * 4 + 3] = r3;
    }

    float* op = out + (size_t)b0 * N + n;

    #pragma unroll
    for (int it = 0; it < 8; ++it) {
        const float2 va = pf[it & 3][0], vb = pf[it & 3][1], vc = pf[it & 3][2];
        if (it < 4) {                              // keep 4-deep steady state
            const float2* q = ip + (size_t)(it + 4) * st;
            pf[it & 3][0] = q[0]; pf[it & 3][1] = q[1]; pf[it & 3][2] = q[2];
        }
        const float x0 = va.x, x1 = va.y, x2 = vb.x,
                    x3 = vb.y, x4 = vc.x, x5 = vc.y;
        const float B0 = 1.0f - x0, B1 = 1.0f - x1, B2 = 1.0f - x2,
                    B3 = 1.0f - x3, B4 = 1.0f - x4, B5 = 1.0f - x5;

        // idx i = b0*32+b1*16 + b2*8+b3*4 + b4*2+b5; bit==0 -> x, bit==1 -> 1-x
        const float t01a[4] = {x0 * x1, x0 * B1, B0 * x1, B0 * B1};
        const float t23a[4] = {x2 * x3, x2 * B3, B2 * x3, B2 * B3};
        const h2 q0 = __builtin_amdgcn_cvt_pkrtz(x4 * x5, x4 * B5);
        const h2 q1 = __builtin_amdgcn_cvt_pkrtz(B4 * x5, B4 * B5);

        float acc = 0.0f;
        #pragma unroll
        for (int g = 0; g < 4; ++g) {
            float sg = 0.0f;
            #pragma unroll
            for (int j = 0; j < 4; ++j) {
                float d = __builtin_amdgcn_fdot2(q0, w2[g * 8 + j * 2 + 0], 0.0f, false);
                d       = __builtin_amdgcn_fdot2(q1, w2[g * 8 + j * 2 + 1], d,    false);
                sg = fmaf(t23a[j], d, sg);
            }
            acc = fmaf(t01a[g], sg, acc);
        }
        op[(size_t)it * 4 * N] = acc;
    }
}

extern "C" void kernel_launch(void* const* d_in, const int* in_sizes, int n_in,
                              void* d_out, int out_size, void* d_ws, size_t ws_size,
                              hipStream_t stream) {
    const float* inputs = (const float*)d_in[0];   // [B, N, 6] f32
    const float* lut    = (const float*)d_in[1];   // [N, 64]  f32
    float* out = (float*)d_out;                    // [B, N]   f32

    const int lut_sz = in_sizes[1];                // N*64
    const int N = lut_sz / 64;
    const int B = in_sizes[0] / (6 * N);

    dim3 grid(N / 64, B / 32);
    lut_kernel<<<grid, 256, 0, stream>>>(inputs, lut, out, N);
}